// Round 8
// baseline (129.603 us; speedup 1.0000x reference)
//
#include <hip/hip_runtime.h>
#include <stdint.h>

#define Bn 4
#define Cn 64
#define Sn 4096
#define Gn 32

typedef float v4f __attribute__((ext_vector_type(4)));
typedef short v8s __attribute__((ext_vector_type(8)));
typedef short v4s __attribute__((ext_vector_type(4)));

#define MFMA16(a,b,c) __builtin_amdgcn_mfma_f32_16x16x32_bf16((a),(b),(c),0,0,0)

#define QSC 0.18033688011112042f   /* (1/sqrt(64)) * log2(e) */

__device__ __forceinline__ float bf2f(uint16_t u){
  union { uint32_t i; float f; } x; x.i = ((uint32_t)u) << 16; return x.f;
}
__device__ __forceinline__ uint16_t f2bf(float f){
  union { float f; uint32_t i; } x; x.f = f;
  uint32_t r = x.i + 0x7fffu + ((x.i >> 16) & 1u);
  return (uint16_t)(r >> 16);
}
__device__ __forceinline__ uint32_t cvtpk(float a, float b){
  uint32_t r;
  asm("v_cvt_pk_bf16_f32 %0, %1, %2" : "=v"(r) : "v"(a), "v"(b));
  return r;   // lo16 = bf16(a), hi16 = bf16(b)
}

// ---------------- kernel 1: GroupNorm stats + weight bf16 pre-convert --------
__global__ __launch_bounds__(256) void gn_stats(
    const float* __restrict__ x,
    const float* __restrict__ wq, const float* __restrict__ wk,
    const float* __restrict__ wv, const float* __restrict__ wp,
    float* __restrict__ stats, uint16_t* __restrict__ Wbf)
{
  const int tid = threadIdx.x;
  if (blockIdx.x >= 128) {
    const int m = blockIdx.x - 128;
    const float* src = (m == 0) ? wq : (m == 1) ? wk : (m == 2) ? wv : wp;
    const float sc  = (m == 0) ? QSC : 1.f;
    uint16_t* dst = Wbf + (m << 12);
    #pragma unroll
    for (int i = 0; i < 4; ++i) {
      const int e = (tid << 4) + (i << 2);
      float4 v = *(const float4*)(src + e);
      v4s o;
      o[0] = (short)f2bf(v.x*sc); o[1] = (short)f2bf(v.y*sc);
      o[2] = (short)f2bf(v.z*sc); o[3] = (short)f2bf(v.w*sc);
      *(v4s*)(dst + e) = o;
    }
    return;
  }
  const float* base = x + (size_t)blockIdx.x * 8192;
  float sum = 0.f, sq = 0.f;
  #pragma unroll
  for (int i = 0; i < 8; ++i) {
    float4 v = *(const float4*)(base + ((i << 8) + tid)*4);
    sum += v.x + v.y + v.z + v.w;
    sq  += v.x*v.x + v.y*v.y + v.z*v.z + v.w*v.w;
  }
  #pragma unroll
  for (int off = 1; off < 64; off <<= 1) {
    sum += __shfl_xor(sum, off);
    sq  += __shfl_xor(sq, off);
  }
  __shared__ float red[8];
  const int w = tid >> 6;
  if ((tid & 63) == 0) { red[w] = sum; red[4+w] = sq; }
  __syncthreads();
  if (tid == 0) {
    float s = red[0]+red[1]+red[2]+red[3];
    float q = red[4]+red[5]+red[6]+red[7];
    float mean = s * (1.f/8192.f);
    float var  = q * (1.f/8192.f) - mean*mean;
    stats[blockIdx.x]       = mean;
    stats[128 + blockIdx.x] = rsqrtf(fmaxf(var, 0.f) + 1e-5f);
  }
}

// ---------------- kernel 2: normalize + QKV projection (16-row tiles) --------
__global__ __launch_bounds__(256) void gn_qkv(
    const float* __restrict__ xg, const float* __restrict__ gamma,
    const float* __restrict__ beta, const uint16_t* __restrict__ Wbf,
    const float* __restrict__ bq, const float* __restrict__ bk,
    const float* __restrict__ bv,
    const float* __restrict__ stats,
    uint16_t* __restrict__ Qg, uint16_t* __restrict__ Kg, uint16_t* __restrict__ Vg)
{
  __shared__ uint16_t Hs[16*72];
  const int tid  = threadIdx.x;
  const int w    = tid >> 6;
  const int lane = tid & 63;
  const int l15  = lane & 15;
  const int quad = lane >> 4;
  const int b      = blockIdx.x >> 8;
  const int s_base = (blockIdx.x & 255) << 4;

  {
    const int c = lane;
    const int g = c >> 1;
    const float mean = stats[b*Gn + g];
    const float rstd = stats[128 + b*Gn + g];
    const float ga = gamma[c], be = beta[c];
    float4 v = *(const float4*)(xg + ((size_t)b*Cn + c)*Sn + s_base + (w << 2));
    const int r0 = w << 2;
    Hs[(r0+0)*72 + c] = f2bf((v.x - mean)*rstd*ga + be);
    Hs[(r0+1)*72 + c] = f2bf((v.y - mean)*rstd*ga + be);
    Hs[(r0+2)*72 + c] = f2bf((v.z - mean)*rstd*ga + be);
    Hs[(r0+3)*72 + c] = f2bf((v.w - mean)*rstd*ga + be);
  }
  __syncthreads();

  v8s bh0 = *(const v8s*)(Hs + l15*72 + (quad << 3));
  v8s bh1 = *(const v8s*)(Hs + l15*72 + 32 + (quad << 3));

  #pragma unroll
  for (int t = 0; t < 3; ++t) {
    const int ot   = w*3 + t;
    const int wsel = ot >> 2;
    const int o16  = (ot & 3) << 4;
    const float* Bsel = (wsel == 0) ? bq : (wsel == 1) ? bk : bv;
    const float bsc   = (wsel == 0) ? QSC : 1.f;
    const uint16_t* Wr = Wbf + (wsel << 12) + (o16 + l15)*64 + (quad << 3);
    v8s a0 = *(const v8s*)(Wr);
    v8s a1 = *(const v8s*)(Wr + 32);
    v4f d = (v4f){0.f,0.f,0.f,0.f};
    d = MFMA16(a0, bh0, d);
    d = MFMA16(a1, bh1, d);
    const int s = s_base + l15;
    if (wsel <= 1) {
      v4s qv;
      #pragma unroll
      for (int r = 0; r < 4; ++r)
        qv[r] = (short)f2bf(d[r] + Bsel[o16 + (quad << 2) + r]*bsc);
      uint16_t* dst = (wsel == 0 ? Qg : Kg) + ((size_t)b*Sn + s)*64 + o16 + (quad << 2);
      *(v4s*)dst = qv;
    } else {
      #pragma unroll
      for (int r = 0; r < 4; ++r) {
        const int o = o16 + (quad << 2) + r;
        Vg[((size_t)b*Cn + o)*Sn + s] = f2bf(d[r] + Bsel[o]);
      }
    }
  }
}

// ---------------- kernel 3: attention, K-from-global, V in LDS ---------------
// grid 1024; XCD decode: split = bx>>7, bq = (bx&7)*16 + ((bx>>3)&15) --
// all 8 splits of one (b,qt) share an XCD L2. block 256 = 4 waves x 32
// queries. ONLY change vs the passing round-6 kernel: K A-fragments are read
// straight from global (L2-resident; vector-mem pipe) instead of staging Ks
// in LDS -- the LDS K path was 4x redundant across waves. V keeps the LDS
// double-buffer (18 KiB). Opart store and proj_res are round-6 verbatim
// (round-7's strip-store + new merge NaN'd; isolating one variable).
// NO setprio (round-5: -16us lockstep). NO device fences (round-4: L2 poison).
__global__ __launch_bounds__(256, 4) void attn_split(
    const uint16_t* __restrict__ Qg, const uint16_t* __restrict__ Kg,
    const uint16_t* __restrict__ Vg,
    uint16_t* __restrict__ Opart, float* __restrict__ lpart)
{
  __shared__ uint16_t Vs[2][64*72];    // [c][j]

  const int tid  = threadIdx.x;
  const int w    = tid >> 6;
  const int lane = tid & 63;
  const int l15  = lane & 15;
  const int quad = lane >> 4;
  const int bx    = blockIdx.x;
  const int split = bx >> 7;                        // 0..7
  const int bq    = (bx & 7)*16 + ((bx >> 3) & 15); // 0..127 = b*32+qt
  const int b     = bq >> 5;
  const int qt    = bq & 31;
  const int slot  = (bq << 3) + split;              // Opart/lpart slot
  const int i_base = qt << 7;
  const int j0     = split << 9;                    // 512 keys per split

  const uint16_t* Qb = Qg + ((size_t)b*Sn + i_base)*64;
  const uint16_t* Kb = Kg + (size_t)b*Sn*64;
  const uint16_t* Vb = Vg + (size_t)b*Cn*Sn;

  // Q as B-operand: col = query = l15 (+16h +32w), k = channel = quad*8+j
  v8s qb[2][2];
  #pragma unroll
  for (int h = 0; h < 2; ++h) {
    const int row = (w << 5) + (h << 4) + l15;
    qb[h][0] = *(const v8s*)(Qb + row*64 + (quad << 3));
    qb[h][1] = *(const v8s*)(Qb + row*64 + 32 + (quad << 3));
  }

  // V staging geometry: thread t covers elems e=t*8 (+2048), row=e>>6, col=e&63
  const int e0 = tid << 3,         r0 = e0 >> 6, c0 = e0 & 63;
  const int e1 = (256 + tid) << 3, r1 = e1 >> 6, c1 = e1 & 63;

  *(v8s*)(Vs[0] + r0*72 + c0) = *(const v8s*)(Vb + (size_t)r0*Sn + j0 + c0);
  *(v8s*)(Vs[0] + r1*72 + c1) = *(const v8s*)(Vb + (size_t)r1*Sn + j0 + c1);

  const v8s ones8 = (v8s){0x3F80,0x3F80,0x3F80,0x3F80,0x3F80,0x3F80,0x3F80,0x3F80};

  v4f o_l[2];
  v4f o_acc[2][4];
  #pragma unroll
  for (int h = 0; h < 2; ++h) {
    o_l[h] = (v4f){0.f,0.f,0.f,0.f};
    #pragma unroll
    for (int nc = 0; nc < 4; ++nc) o_acc[h][nc] = (v4f){0.f,0.f,0.f,0.f};
  }

  __syncthreads();

  for (int kt = 0; kt < 8; ++kt) {
    const int cur = kt & 1;

    // K A-fragments from global: row = key = n*16+l15, k = channel
    // (identical addressing to the former LDS path: K[j0+kt*64+n*16+l15][quad*8+j])
    const uint16_t* Kt = Kb + (size_t)(j0 + (kt << 6))*64;
    v8s ka[4][2];
    #pragma unroll
    for (int n = 0; n < 4; ++n) {
      const uint16_t* kr = Kt + ((n << 4) + l15)*64 + (quad << 3);
      ka[n][0] = *(const v8s*)(kr);
      ka[n][1] = *(const v8s*)(kr + 32);
    }

    // V prefetch for next tile (latency hides under compute)
    v8s vp0, vp1;
    if (kt < 7) {
      const int jb = j0 + ((kt + 1) << 6);
      vp0 = *(const v8s*)(Vb + (size_t)r0*Sn + jb + c0);
      vp1 = *(const v8s*)(Vb + (size_t)r1*Sn + jb + c1);
    }

    // S^T = K Q^T : lane holds S[key = n*16+quad*4+r][query = l15]
    v8s pa[2][2];
    #pragma unroll
    for (int h = 0; h < 2; ++h) {
      v4f s[4];
      #pragma unroll
      for (int n = 0; n < 4; ++n) {
        v4f t = (v4f){0.f,0.f,0.f,0.f};
        t = MFMA16(ka[n][0], qb[h][0], t);
        t = MFMA16(ka[n][1], qb[h][1], t);
        s[n] = t;
      }
      union { v8s s8; uint32_t u[4]; } u0, u1;
      #pragma unroll
      for (int n = 0; n < 4; ++n) {
        const float p0 = __builtin_amdgcn_exp2f(s[n][0]);
        const float p1 = __builtin_amdgcn_exp2f(s[n][1]);
        const float p2 = __builtin_amdgcn_exp2f(s[n][2]);
        const float p3 = __builtin_amdgcn_exp2f(s[n][3]);
        const uint32_t w0 = cvtpk(p0, p1);
        const uint32_t w1 = cvtpk(p2, p3);
        if (n < 2) { u0.u[(n & 1)*2] = w0; u0.u[(n & 1)*2 + 1] = w1; }
        else       { u1.u[(n & 1)*2] = w0; u1.u[(n & 1)*2 + 1] = w1; }
      }
      pa[h][0] = u0.s8;
      pa[h][1] = u1.s8;
      // softmax denominator on the MFMA pipe
      o_l[h] = MFMA16(pa[h][0], ones8, o_l[h]);
      o_l[h] = MFMA16(pa[h][1], ones8, o_l[h]);
    }

    // O += P V : k' relabel key(c,k') = c*32 + (k'&4?16:0) + (k'>>3)*4 + (k'&3)
    #pragma unroll
    for (int nc = 0; nc < 4; ++nc) {
      const uint16_t* vrow = Vs[cur] + ((nc << 4) + l15)*72;
      #pragma unroll
      for (int c = 0; c < 2; ++c) {
        union { v8s s8; v4s h4[2]; } vb;
        vb.h4[0] = *(const v4s*)(vrow + (c << 5) + (quad << 2));
        vb.h4[1] = *(const v4s*)(vrow + (c << 5) + 16 + (quad << 2));
        o_acc[0][nc] = MFMA16(pa[0][c], vb.s8, o_acc[0][nc]);
        o_acc[1][nc] = MFMA16(pa[1][c], vb.s8, o_acc[1][nc]);
      }
    }

    if (kt < 7) {
      const int nxt = cur ^ 1;
      *(v8s*)(Vs[nxt] + r0*72 + c0) = vp0;
      *(v8s*)(Vs[nxt] + r1*72 + c1) = vp1;
      __syncthreads();
    }
  }

  // O layout from PV mfma: row = query = h*16+quad*4+r (+32w), col = ch = nc*16+l15
  uint16_t* Ob = Opart + (size_t)slot*8192 + (size_t)(w << 5)*64;
  float*    lp = lpart + slot*128 + (w << 5);
  #pragma unroll
  for (int h = 0; h < 2; ++h)
    #pragma unroll
    for (int nc = 0; nc < 4; ++nc)
      #pragma unroll
      for (int r = 0; r < 4; ++r)
        Ob[((h << 4) + (quad << 2) + r)*64 + (nc << 4) + l15] = f2bf(o_acc[h][nc][r]);
  // o_l lane (quad, any l15) reg r = lsum for query h*16 + quad*4 + r
  if (l15 == 0) {
    #pragma unroll
    for (int h = 0; h < 2; ++h)
      #pragma unroll
      for (int r = 0; r < 4; ++r)
        lp[(h << 4) + (quad << 2) + r] = o_l[h][r];
  }
}

// ---------------- kernel 4: merge 8 splits + projection + residual -----------
__global__ __launch_bounds__(256) void proj_res(
    const uint16_t* __restrict__ Opart, const float* __restrict__ lpart,
    const uint16_t* __restrict__ Wbf, const float* __restrict__ bp,
    const float* __restrict__ xg, float* __restrict__ out)
{
  __shared__ uint16_t As[16*72];
  const int tid  = threadIdx.x;
  const int w    = tid >> 6;
  const int lane = tid & 63;
  const int l15  = lane & 15;
  const int quad = lane >> 4;
  const int b      = blockIdx.x >> 8;
  const int st     = blockIdx.x & 255;
  const int qt     = st >> 3;          // 128-query tile
  const int sub    = st & 7;           // 16-row subtile within it
  const int s_base = st << 4;

  const uint16_t* po = Opart + (size_t)((b*32 + qt)*8)*8192 + (sub << 4)*64;
  const float*    pl = lpart + ((b*32 + qt)*8)*128 + (sub << 4);

  {
    const int e = tid << 2, row = tid >> 4, col = (tid & 15) << 2;
    float lsum = 0.f;
    #pragma unroll
    for (int sp = 0; sp < 8; ++sp) lsum += pl[sp*128 + row];
    const float linv = 1.f / lsum;
    float acc[4] = {0.f,0.f,0.f,0.f};
    #pragma unroll
    for (int sp = 0; sp < 8; ++sp) {
      v4s o = *(const v4s*)(po + (size_t)sp*8192 + e);
      #pragma unroll
      for (int j = 0; j < 4; ++j) acc[j] += bf2f((uint16_t)o[j]);
    }
    v4s a;
    #pragma unroll
    for (int j = 0; j < 4; ++j) a[j] = (short)f2bf(acc[j]*linv);
    *(v4s*)(As + row*72 + col) = a;
  }
  __syncthreads();

  v8s ba0 = *(const v8s*)(As + l15*72 + (quad << 3));
  v8s ba1 = *(const v8s*)(As + l15*72 + 32 + (quad << 3));

  const uint16_t* Wr = Wbf + (3 << 12) + ((w << 4) + l15)*64 + (quad << 3);
  v8s a0 = *(const v8s*)(Wr);
  v8s a1 = *(const v8s*)(Wr + 32);
  v4f d = (v4f){0.f,0.f,0.f,0.f};
  d = MFMA16(a0, ba0, d);
  d = MFMA16(a1, ba1, d);
  const int s = s_base + l15;
  #pragma unroll
  for (int r = 0; r < 4; ++r) {
    const int o = (w << 4) + (quad << 2) + r;
    const size_t idx = ((size_t)b*Cn + o)*Sn + s;
    out[idx] = d[r] + bp[o] + xg[idx];
  }
}

extern "C" void kernel_launch(void* const* d_in, const int* in_sizes, int n_in,
                              void* d_out, int out_size, void* d_ws, size_t ws_size,
                              hipStream_t stream)
{
  const float* x     = (const float*)d_in[0];
  const float* gamma = (const float*)d_in[1];
  const float* beta  = (const float*)d_in[2];
  const float* wq    = (const float*)d_in[3];
  const float* bq    = (const float*)d_in[4];
  const float* wk    = (const float*)d_in[5];
  const float* bk    = (const float*)d_in[6];
  const float* wv    = (const float*)d_in[7];
  const float* bv    = (const float*)d_in[8];
  const float* wp    = (const float*)d_in[9];
  const float* bp    = (const float*)d_in[10];

  float*    stats = (float*)d_ws;                        // 256 f32
  uint16_t* Wbf   = (uint16_t*)d_ws + 2048;              // 4 x 64x64 bf16 (32 KiB)
  uint16_t* Qg    = (uint16_t*)d_ws + 32768;             // [B][S][C] bf16 (2 MiB)
  uint16_t* Kg    = Qg + (size_t)Bn*Sn*Cn;               // [B][S][C]
  uint16_t* Vg    = Kg + (size_t)Bn*Sn*Cn;               // [B][C][S]
  uint16_t* Opart = Vg + (size_t)Bn*Sn*Cn;               // 1024 x 128 x 64 bf16 (16 MiB)
  float*    lpart = (float*)(Opart + (size_t)1024*8192); // 1024 x 128 f32 (512 KiB)
  float*    outp  = (float*)d_out;

  gn_stats  <<<132, 256, 0, stream>>>(x, wq, wk, wv, wp, stats, Wbf);
  gn_qkv    <<<1024, 256, 0, stream>>>(x, gamma, beta, Wbf, bq, bk, bv,
                                       stats, Qg, Kg, Vg);
  attn_split<<<1024, 256, 0, stream>>>(Qg, Kg, Vg, Opart, lpart);
  proj_res  <<<1024, 256, 0, stream>>>(Opart, lpart, Wbf, bp, x, outp);
}

// Round 9
// 113.445 us; speedup vs baseline: 1.1424x; 1.1424x over previous
//
#include <hip/hip_runtime.h>
#include <stdint.h>

#define Bn 4
#define Cn 64
#define Sn 4096
#define Gn 32

typedef float v4f __attribute__((ext_vector_type(4)));
typedef short v8s __attribute__((ext_vector_type(8)));
typedef short v4s __attribute__((ext_vector_type(4)));

#define MFMA16(a,b,c) __builtin_amdgcn_mfma_f32_16x16x32_bf16((a),(b),(c),0,0,0)

#define QSC 0.18033688011112042f   /* (1/sqrt(64)) * log2(e) */

__device__ __forceinline__ float bf2f(uint16_t u){
  union { uint32_t i; float f; } x; x.i = ((uint32_t)u) << 16; return x.f;
}
__device__ __forceinline__ uint16_t f2bf(float f){
  union { float f; uint32_t i; } x; x.f = f;
  uint32_t r = x.i + 0x7fffu + ((x.i >> 16) & 1u);
  return (uint16_t)(r >> 16);
}
__device__ __forceinline__ uint32_t cvtpk(float a, float b){
  uint32_t r;
  asm("v_cvt_pk_bf16_f32 %0, %1, %2" : "=v"(r) : "v"(a), "v"(b));
  return r;   // lo16 = bf16(a), hi16 = bf16(b)
}

// ---------------- kernel 1: GroupNorm stats + weight bf16 pre-convert --------
__global__ __launch_bounds__(256) void gn_stats(
    const float* __restrict__ x,
    const float* __restrict__ wq, const float* __restrict__ wk,
    const float* __restrict__ wv, const float* __restrict__ wp,
    float* __restrict__ stats, uint16_t* __restrict__ Wbf)
{
  const int tid = threadIdx.x;
  if (blockIdx.x >= 128) {
    const int m = blockIdx.x - 128;
    const float* src = (m == 0) ? wq : (m == 1) ? wk : (m == 2) ? wv : wp;
    const float sc  = (m == 0) ? QSC : 1.f;
    uint16_t* dst = Wbf + (m << 12);
    #pragma unroll
    for (int i = 0; i < 4; ++i) {
      const int e = (tid << 4) + (i << 2);
      float4 v = *(const float4*)(src + e);
      v4s o;
      o[0] = (short)f2bf(v.x*sc); o[1] = (short)f2bf(v.y*sc);
      o[2] = (short)f2bf(v.z*sc); o[3] = (short)f2bf(v.w*sc);
      *(v4s*)(dst + e) = o;
    }
    return;
  }
  const float* base = x + (size_t)blockIdx.x * 8192;
  float sum = 0.f, sq = 0.f;
  #pragma unroll
  for (int i = 0; i < 8; ++i) {
    float4 v = *(const float4*)(base + ((i << 8) + tid)*4);
    sum += v.x + v.y + v.z + v.w;
    sq  += v.x*v.x + v.y*v.y + v.z*v.z + v.w*v.w;
  }
  #pragma unroll
  for (int off = 1; off < 64; off <<= 1) {
    sum += __shfl_xor(sum, off);
    sq  += __shfl_xor(sq, off);
  }
  __shared__ float red[8];
  const int w = tid >> 6;
  if ((tid & 63) == 0) { red[w] = sum; red[4+w] = sq; }
  __syncthreads();
  if (tid == 0) {
    float s = red[0]+red[1]+red[2]+red[3];
    float q = red[4]+red[5]+red[6]+red[7];
    float mean = s * (1.f/8192.f);
    float var  = q * (1.f/8192.f) - mean*mean;
    stats[blockIdx.x]       = mean;
    stats[128 + blockIdx.x] = rsqrtf(fmaxf(var, 0.f) + 1e-5f);
  }
}

// ---------------- kernel 2: normalize + QKV projection, coalesced -----------
// grid 512: bx = b*128 + tile; block covers 64 channels x 32 spatial.
// x loads are lane-consecutive in SPATIAL (128B runs) -- the old per-lane
// channel-row float4 pattern was 64 scattered 16B requests per wave.
// Weight fragments + biases hoisted to registers (were re-read per block).
__global__ __launch_bounds__(256) void gn_qkv(
    const float* __restrict__ xg, const float* __restrict__ gamma,
    const float* __restrict__ beta, const uint16_t* __restrict__ Wbf,
    const float* __restrict__ bq, const float* __restrict__ bk,
    const float* __restrict__ bv,
    const float* __restrict__ stats,
    uint16_t* __restrict__ Qg, uint16_t* __restrict__ Kg, uint16_t* __restrict__ Vg)
{
  __shared__ uint16_t Hs[32*72];       // [s_local][c]
  const int tid  = threadIdx.x;
  const int w    = tid >> 6;
  const int lane = tid & 63;
  const int l15  = lane & 15;
  const int quad = lane >> 4;
  const int b  = blockIdx.x >> 7;
  const int s0 = (blockIdx.x & 127) << 5;

  // phase 1: 512 float4 loads, idx -> (channel = idx>>3, float4-col = idx&7)
  #pragma unroll
  for (int i = 0; i < 2; ++i) {
    const int idx  = (i << 8) + tid;
    const int c    = idx >> 3;
    const int col4 = idx & 7;
    const int g    = c >> 1;
    const float mean = stats[b*Gn + g];
    const float rstd = stats[128 + b*Gn + g];
    const float ga = gamma[c], be = beta[c];
    float4 v = *(const float4*)(xg + ((size_t)b*Cn + c)*Sn + s0 + (col4 << 2));
    const int sl = col4 << 2;
    Hs[(sl+0)*72 + c] = f2bf((v.x - mean)*rstd*ga + be);
    Hs[(sl+1)*72 + c] = f2bf((v.y - mean)*rstd*ga + be);
    Hs[(sl+2)*72 + c] = f2bf((v.z - mean)*rstd*ga + be);
    Hs[(sl+3)*72 + c] = f2bf((v.w - mean)*rstd*ga + be);
  }
  __syncthreads();

  // phase 2: hoist this wave's 3 projections (weights + scaled bias)
  v8s  wa0[3], wa1[3];
  float bias[3][4];
  #pragma unroll
  for (int t = 0; t < 3; ++t) {
    const int ot   = w*3 + t;
    const int wsel = ot >> 2;
    const int o16  = (ot & 3) << 4;
    const float* Bsel = (wsel == 0) ? bq : (wsel == 1) ? bk : bv;
    const float bsc   = (wsel == 0) ? QSC : 1.f;
    const uint16_t* Wr = Wbf + (wsel << 12) + (o16 + l15)*64 + (quad << 3);
    wa0[t] = *(const v8s*)(Wr);
    wa1[t] = *(const v8s*)(Wr + 32);
    #pragma unroll
    for (int r = 0; r < 4; ++r) bias[t][r] = Bsel[o16 + (quad << 2) + r]*bsc;
  }

  #pragma unroll
  for (int sub = 0; sub < 2; ++sub) {
    const uint16_t* hr = Hs + ((sub << 4) + l15)*72;
    v8s bh0 = *(const v8s*)(hr + (quad << 3));
    v8s bh1 = *(const v8s*)(hr + 32 + (quad << 3));
    const int s = s0 + (sub << 4) + l15;
    #pragma unroll
    for (int t = 0; t < 3; ++t) {
      const int ot   = w*3 + t;
      const int wsel = ot >> 2;
      const int o16  = (ot & 3) << 4;
      v4f d = (v4f){0.f,0.f,0.f,0.f};
      d = MFMA16(wa0[t], bh0, d);
      d = MFMA16(wa1[t], bh1, d);
      if (wsel <= 1) {
        v4s qv;
        #pragma unroll
        for (int r = 0; r < 4; ++r) qv[r] = (short)f2bf(d[r] + bias[t][r]);
        uint16_t* dst = (wsel == 0 ? Qg : Kg) + ((size_t)b*Sn + s)*64 + o16 + (quad << 2);
        *(v4s*)dst = qv;
      } else {
        #pragma unroll
        for (int r = 0; r < 4; ++r) {
          const int o = o16 + (quad << 2) + r;
          Vg[((size_t)b*Cn + o)*Sn + s] = f2bf(d[r] + bias[t][r]);
        }
      }
    }
  }
}

// ---------------- kernel 3: attention (round-6 verbatim; best verified) ------
// grid 1024; XCD decode: split = bx>>7, bq = (bx&7)*16 + ((bx>>3)&15).
// Ks/Vs LDS double-buffer (36 KiB, 4 blocks/CU). K-from-global regressed
// (round-8: +15us, latency-bound); setprio regressed (round-5: -16us);
// device fences regressed (round-4: L2 poison). This structure stands.
__global__ __launch_bounds__(256, 4) void attn_split(
    const uint16_t* __restrict__ Qg, const uint16_t* __restrict__ Kg,
    const uint16_t* __restrict__ Vg,
    uint16_t* __restrict__ Opart, float* __restrict__ lpart)
{
  __shared__ uint16_t Ks[2][64*72];    // [j][c]
  __shared__ uint16_t Vs[2][64*72];    // [c][j]

  const int tid  = threadIdx.x;
  const int w    = tid >> 6;
  const int lane = tid & 63;
  const int l15  = lane & 15;
  const int quad = lane >> 4;
  const int bx    = blockIdx.x;
  const int split = bx >> 7;                        // 0..7
  const int bq    = (bx & 7)*16 + ((bx >> 3) & 15); // 0..127 = b*32+qt
  const int b     = bq >> 5;
  const int qt    = bq & 31;
  const int slot  = (bq << 3) + split;              // Opart/lpart slot
  const int i_base = qt << 7;
  const int j0     = split << 9;                    // 512 keys per split

  const uint16_t* Qb = Qg + ((size_t)b*Sn + i_base)*64;
  const uint16_t* Kb = Kg + (size_t)b*Sn*64;
  const uint16_t* Vb = Vg + (size_t)b*Cn*Sn;

  v8s qb[2][2];
  #pragma unroll
  for (int h = 0; h < 2; ++h) {
    const int row = (w << 5) + (h << 4) + l15;
    qb[h][0] = *(const v8s*)(Qb + row*64 + (quad << 3));
    qb[h][1] = *(const v8s*)(Qb + row*64 + 32 + (quad << 3));
  }

  const int e0 = tid << 3,         r0 = e0 >> 6, c0 = e0 & 63;
  const int e1 = (256 + tid) << 3, r1 = e1 >> 6, c1 = e1 & 63;

  *(v8s*)(Ks[0] + r0*72 + c0) = *(const v8s*)(Kb + j0*64 + e0);
  *(v8s*)(Ks[0] + r1*72 + c1) = *(const v8s*)(Kb + j0*64 + e1);
  *(v8s*)(Vs[0] + r0*72 + c0) = *(const v8s*)(Vb + (size_t)r0*Sn + j0 + c0);
  *(v8s*)(Vs[0] + r1*72 + c1) = *(const v8s*)(Vb + (size_t)r1*Sn + j0 + c1);

  const v8s ones8 = (v8s){0x3F80,0x3F80,0x3F80,0x3F80,0x3F80,0x3F80,0x3F80,0x3F80};

  v4f o_l[2];
  v4f o_acc[2][4];
  #pragma unroll
  for (int h = 0; h < 2; ++h) {
    o_l[h] = (v4f){0.f,0.f,0.f,0.f};
    #pragma unroll
    for (int nc = 0; nc < 4; ++nc) o_acc[h][nc] = (v4f){0.f,0.f,0.f,0.f};
  }

  __syncthreads();

  for (int kt = 0; kt < 8; ++kt) {
    const int cur = kt & 1;
    v8s kp0, kp1, vp0, vp1;
    if (kt < 7) {
      const int jb = j0 + ((kt + 1) << 6);
      kp0 = *(const v8s*)(Kb + jb*64 + e0);
      kp1 = *(const v8s*)(Kb + jb*64 + e1);
      vp0 = *(const v8s*)(Vb + (size_t)r0*Sn + jb + c0);
      vp1 = *(const v8s*)(Vb + (size_t)r1*Sn + jb + c1);
    }

    v8s ka[4][2];
    #pragma unroll
    for (int n = 0; n < 4; ++n) {
      const uint16_t* kr = Ks[cur] + ((n << 4) + l15)*72;
      ka[n][0] = *(const v8s*)(kr + (quad << 3));
      ka[n][1] = *(const v8s*)(kr + 32 + (quad << 3));
    }

    // S^T = K Q^T : lane holds S[key = n*16+quad*4+r][query = l15]
    v8s pa[2][2];
    #pragma unroll
    for (int h = 0; h < 2; ++h) {
      v4f s[4];
      #pragma unroll
      for (int n = 0; n < 4; ++n) {
        v4f t = (v4f){0.f,0.f,0.f,0.f};
        t = MFMA16(ka[n][0], qb[h][0], t);
        t = MFMA16(ka[n][1], qb[h][1], t);
        s[n] = t;
      }
      union { v8s s8; uint32_t u[4]; } u0, u1;
      #pragma unroll
      for (int n = 0; n < 4; ++n) {
        const float p0 = __builtin_amdgcn_exp2f(s[n][0]);
        const float p1 = __builtin_amdgcn_exp2f(s[n][1]);
        const float p2 = __builtin_amdgcn_exp2f(s[n][2]);
        const float p3 = __builtin_amdgcn_exp2f(s[n][3]);
        const uint32_t w0 = cvtpk(p0, p1);
        const uint32_t w1 = cvtpk(p2, p3);
        if (n < 2) { u0.u[(n & 1)*2] = w0; u0.u[(n & 1)*2 + 1] = w1; }
        else       { u1.u[(n & 1)*2] = w0; u1.u[(n & 1)*2 + 1] = w1; }
      }
      pa[h][0] = u0.s8;
      pa[h][1] = u1.s8;
      o_l[h] = MFMA16(pa[h][0], ones8, o_l[h]);
      o_l[h] = MFMA16(pa[h][1], ones8, o_l[h]);
    }

    // O += P V : k' relabel key(c,k') = c*32 + (k'&4?16:0) + (k'>>3)*4 + (k'&3)
    #pragma unroll
    for (int nc = 0; nc < 4; ++nc) {
      const uint16_t* vrow = Vs[cur] + ((nc << 4) + l15)*72;
      #pragma unroll
      for (int c = 0; c < 2; ++c) {
        union { v8s s8; v4s h4[2]; } vb;
        vb.h4[0] = *(const v4s*)(vrow + (c << 5) + (quad << 2));
        vb.h4[1] = *(const v4s*)(vrow + (c << 5) + 16 + (quad << 2));
        o_acc[0][nc] = MFMA16(pa[0][c], vb.s8, o_acc[0][nc]);
        o_acc[1][nc] = MFMA16(pa[1][c], vb.s8, o_acc[1][nc]);
      }
    }

    if (kt < 7) {
      const int nxt = cur ^ 1;
      *(v8s*)(Ks[nxt] + r0*72 + c0) = kp0;
      *(v8s*)(Ks[nxt] + r1*72 + c1) = kp1;
      *(v8s*)(Vs[nxt] + r0*72 + c0) = vp0;
      *(v8s*)(Vs[nxt] + r1*72 + c1) = vp1;
      __syncthreads();
    }
  }

  uint16_t* Ob = Opart + (size_t)slot*8192 + (size_t)(w << 5)*64;
  float*    lp = lpart + slot*128 + (w << 5);
  #pragma unroll
  for (int h = 0; h < 2; ++h)
    #pragma unroll
    for (int nc = 0; nc < 4; ++nc)
      #pragma unroll
      for (int r = 0; r < 4; ++r)
        Ob[((h << 4) + (quad << 2) + r)*64 + (nc << 4) + l15] = f2bf(o_acc[h][nc][r]);
  if (l15 == 0) {
    #pragma unroll
    for (int h = 0; h < 2; ++h)
      #pragma unroll
      for (int r = 0; r < 4; ++r)
        lp[(h << 4) + (quad << 2) + r] = o_l[h][r];
  }
}

// ---------------- kernel 4: merge 8 splits + projection + residual -----------
// grid 256: each block loops over 4 original 16-row tiles (round-6 body
// verbatim inside the rep loop); Wp fragment + bias hoisted.
__global__ __launch_bounds__(256) void proj_res(
    const uint16_t* __restrict__ Opart, const float* __restrict__ lpart,
    const uint16_t* __restrict__ Wbf, const float* __restrict__ bp,
    const float* __restrict__ xg, float* __restrict__ out)
{
  __shared__ uint16_t As[16*72];
  const int tid  = threadIdx.x;
  const int w    = tid >> 6;
  const int lane = tid & 63;
  const int l15  = lane & 15;
  const int quad = lane >> 4;

  const uint16_t* Wr = Wbf + (3 << 12) + ((w << 4) + l15)*64 + (quad << 3);
  const v8s a0 = *(const v8s*)(Wr);
  const v8s a1 = *(const v8s*)(Wr + 32);
  float bpv[4];
  #pragma unroll
  for (int r = 0; r < 4; ++r) bpv[r] = bp[(w << 4) + (quad << 2) + r];

  for (int rep = 0; rep < 4; ++rep) {
    const int vbx = (blockIdx.x << 2) + rep;
    const int b      = vbx >> 8;
    const int st     = vbx & 255;
    const int qt     = st >> 3;
    const int sub    = st & 7;
    const int s_base = st << 4;
    const uint16_t* po = Opart + (size_t)((b*32 + qt)*8)*8192 + (sub << 4)*64;
    const float*    pl = lpart + ((b*32 + qt)*8)*128 + (sub << 4);

    if (rep) __syncthreads();   // prior rep's As reads complete

    {
      const int e = tid << 2, row = tid >> 4, col = (tid & 15) << 2;
      float lsum = 0.f;
      #pragma unroll
      for (int sp = 0; sp < 8; ++sp) lsum += pl[sp*128 + row];
      const float linv = 1.f / lsum;
      float acc[4] = {0.f,0.f,0.f,0.f};
      #pragma unroll
      for (int sp = 0; sp < 8; ++sp) {
        v4s o = *(const v4s*)(po + (size_t)sp*8192 + e);
        #pragma unroll
        for (int j = 0; j < 4; ++j) acc[j] += bf2f((uint16_t)o[j]);
      }
      v4s a;
      #pragma unroll
      for (int j = 0; j < 4; ++j) a[j] = (short)f2bf(acc[j]*linv);
      *(v4s*)(As + row*72 + col) = a;
    }
    __syncthreads();

    v8s ba0 = *(const v8s*)(As + l15*72 + (quad << 3));
    v8s ba1 = *(const v8s*)(As + l15*72 + 32 + (quad << 3));
    v4f d = (v4f){0.f,0.f,0.f,0.f};
    d = MFMA16(a0, ba0, d);
    d = MFMA16(a1, ba1, d);
    const int s = s_base + l15;
    #pragma unroll
    for (int r = 0; r < 4; ++r) {
      const int o = (w << 4) + (quad << 2) + r;
      const size_t idx = ((size_t)b*Cn + o)*Sn + s;
      out[idx] = d[r] + bpv[r] + xg[idx];
    }
  }
}

extern "C" void kernel_launch(void* const* d_in, const int* in_sizes, int n_in,
                              void* d_out, int out_size, void* d_ws, size_t ws_size,
                              hipStream_t stream)
{
  const float* x     = (const float*)d_in[0];
  const float* gamma = (const float*)d_in[1];
  const float* beta  = (const float*)d_in[2];
  const float* wq    = (const float*)d_in[3];
  const float* bq    = (const float*)d_in[4];
  const float* wk    = (const float*)d_in[5];
  const float* bk    = (const float*)d_in[6];
  const float* wv    = (const float*)d_in[7];
  const float* bv    = (const float*)d_in[8];
  const float* wp    = (const float*)d_in[9];
  const float* bp    = (const float*)d_in[10];

  float*    stats = (float*)d_ws;                        // 256 f32
  uint16_t* Wbf   = (uint16_t*)d_ws + 2048;              // 4 x 64x64 bf16 (32 KiB)
  uint16_t* Qg    = (uint16_t*)d_ws + 32768;             // [B][S][C] bf16 (2 MiB)
  uint16_t* Kg    = Qg + (size_t)Bn*Sn*Cn;               // [B][S][C]
  uint16_t* Vg    = Kg + (size_t)Bn*Sn*Cn;               // [B][C][S]
  uint16_t* Opart = Vg + (size_t)Bn*Sn*Cn;               // 1024 x 128 x 64 bf16 (16 MiB)
  float*    lpart = (float*)(Opart + (size_t)1024*8192); // 1024 x 128 f32 (512 KiB)
  float*    outp  = (float*)d_out;

  gn_stats  <<<132, 256, 0, stream>>>(x, wq, wk, wv, wp, stats, Wbf);
  gn_qkv    <<<512, 256, 0, stream>>>(x, gamma, beta, Wbf, bq, bk, bv,
                                      stats, Qg, Kg, Vg);
  attn_split<<<1024, 256, 0, stream>>>(Qg, Kg, Vg, Opart, lpart);
  proj_res  <<<256, 256, 0, stream>>>(Opart, lpart, Wbf, bp, x, outp);
}